// Round 14
// baseline (103.540 us; speedup 1.0000x reference)
//
#include <hip/hip_runtime.h>

typedef __attribute__((ext_vector_type(8))) short short8;
typedef __attribute__((ext_vector_type(16))) float f32x16;
typedef _Float16 h8 __attribute__((ext_vector_type(8)));
typedef unsigned int uint;
typedef unsigned short ushort;

#define NS 2048
#define QSCALE 0.0901684400555602f  // log2(e)/16, folded into Wq/bq

__device__ __forceinline__ ushort f2h(float f) {
  _Float16 h = (_Float16)f;
  return __builtin_bit_cast(ushort, h);
}
// two f32 -> packed 2xf16 (round toward zero)
__device__ __forceinline__ uint pkrtz_u(float a, float b) {
  uint r;
  asm("v_cvt_pkrtz_f16_f32 %0, %1, %2" : "=v"(r) : "v"(a), "v"(b));
  return r;
}
__device__ __forceinline__ float fast_exp2(float x) {
#if __has_builtin(__builtin_amdgcn_exp2f)
  return __builtin_amdgcn_exp2f(x);
#else
  return exp2f(x);
#endif
}

// =================== kernel 1: QKV projections via f16 MFMA (R13 version) ===================
// p=0: Q (scaled by QSCALE) -> Qh [BH][S][16] f16 ; p=1: K -> Kh ; p=2: V -> Vt [BH*16][S]
__global__ __launch_bounds__(256) void qkv_mfma(
    const float* __restrict__ qin, const float* __restrict__ kin, const float* __restrict__ vin,
    const float* __restrict__ Wq, const float* __restrict__ bq,
    const float* __restrict__ Wk, const float* __restrict__ bk,
    const float* __restrict__ Wv, const float* __restrict__ bv,
    ushort* __restrict__ Qh, ushort* __restrict__ Kh, ushort* __restrict__ Vt) {
  __shared__ __align__(16) ushort Wt[128 * 136];  // Wt[n][k], stride 136
  __shared__ __align__(16) ushort Al[64 * 136];   // Al[m][k]
  const int tid = threadIdx.x;
  const int p = blockIdx.y;
  const float* A = (p == 0) ? qin : (p == 1) ? kin : vin;
  const float* W = (p == 0) ? Wq : (p == 1) ? Wk : Wv;
  const float* bias = (p == 0) ? bq : (p == 1) ? bk : bv;
  const float wscale = (p == 0) ? QSCALE : 1.0f;
  const int rbase = blockIdx.x * 64;
  {
    const int n = tid & 127, kg = tid >> 7;
#pragma unroll
    for (int k8 = 0; k8 < 8; ++k8) {
      int k0 = k8 * 16 + kg * 8;
      float w[8];
#pragma unroll
      for (int j = 0; j < 8; ++j) w[j] = W[(k0 + j) * 128 + n] * wscale;
      uint4 pk;
      pk.x = pkrtz_u(w[0], w[1]);
      pk.y = pkrtz_u(w[2], w[3]);
      pk.z = pkrtz_u(w[4], w[5]);
      pk.w = pkrtz_u(w[6], w[7]);
      *reinterpret_cast<uint4*>(&Wt[n * 136 + k0]) = pk;
    }
  }
#pragma unroll
  for (int it = 0; it < 8; ++it) {
    int fl = it * 256 + tid;
    int r = fl >> 5, c4 = (fl & 31) << 2;
    float4 a = *reinterpret_cast<const float4*>(A + (size_t)(rbase + r) * 128 + c4);
    uint2 pk;
    pk.x = pkrtz_u(a.x, a.y);
    pk.y = pkrtz_u(a.z, a.w);
    *reinterpret_cast<uint2*>(&Al[r * 136 + c4]) = pk;
  }
  __syncthreads();
  const int lane = tid & 63, wid = tid >> 6;
  const int l31 = lane & 31, hi = lane >> 5;
  const int rh = wid >> 1, ch = wid & 1;
  f32x16 acc[2];
#pragma unroll
  for (int i = 0; i < 2; ++i)
#pragma unroll
    for (int j = 0; j < 16; ++j) acc[i][j] = 0.f;
  const ushort* arow = &Al[(rh * 32 + l31) * 136 + hi * 8];
#pragma unroll
  for (int kk = 0; kk < 8; ++kk) {
    const h8 af = *reinterpret_cast<const h8*>(arow + kk * 16);
#pragma unroll
    for (int i = 0; i < 2; ++i) {
      int nt = ch * 2 + i;
      const h8 bf = *reinterpret_cast<const h8*>(&Wt[(nt * 32 + l31) * 136 + kk * 16 + hi * 8]);
      acc[i] = __builtin_amdgcn_mfma_f32_32x32x16_f16(af, bf, acc[i], 0, 0, 0);
    }
  }
  const int bI = rbase >> 11;
  if (p < 2) {
    ushort* outp = (p == 0) ? Qh : Kh;
#pragma unroll
    for (int i = 0; i < 2; ++i) {
      int c = (ch * 2 + i) * 32 + l31;
      int h = c >> 4, d = c & 15;
      float bb = bias[c] * wscale;
#pragma unroll
      for (int r = 0; r < 16; ++r) {
        int s = rbase + rh * 32 + ((r & 3) + ((r >> 2) << 3) + (hi << 2));
        int sl = s & 2047;
        outp[((size_t)((bI << 3) + h) * 2048 + sl) * 16 + d] = f2h(acc[i][r] + bb);
      }
    }
  } else {
    __syncthreads();
    ushort* CL = Wt;  // reuse as [c][s_local], stride 72
#pragma unroll
    for (int i = 0; i < 2; ++i) {
      int c = (ch * 2 + i) * 32 + l31;
      float bb = bias[c];
#pragma unroll
      for (int g = 0; g < 4; ++g) {
        uint2 pk;
        pk.x = pkrtz_u(acc[i][g * 4 + 0] + bb, acc[i][g * 4 + 1] + bb);
        pk.y = pkrtz_u(acc[i][g * 4 + 2] + bb, acc[i][g * 4 + 3] + bb);
        int sl0 = rh * 32 + g * 8 + (hi << 2);
        *reinterpret_cast<uint2*>(&CL[c * 72 + sl0]) = pk;
      }
    }
    __syncthreads();
    const int slb = rbase & 2047;
#pragma unroll
    for (int it = 0; it < 4; ++it) {
      int fl = it * 256 + tid;
      int c = fl >> 3, s8 = (fl & 7) * 8;
      short8 val = *reinterpret_cast<const short8*>(&CL[c * 72 + s8]);
      int h = c >> 4, d = c & 15;
      *reinterpret_cast<short8*>(&Vt[((size_t)((bI << 3) + h) * 16 + d) * 2048 + slb + s8]) = val;
    }
  }
}

// =================== kernel 2: flash attention — LDS-free, barrier-free ===================
// Grid (bh=x, qt=y): all 16 q-tiles of a head share one XCD -> K/V (128KB/head) L2-resident.
// K/V fragments are read DIRECTLY from global (L2-hot) each iteration:
//   kf = Kh[(kb+l31)*16 + hi*8]  (layout is exactly fragment order, one b128)
//   vf = two 8B reads of Vt rows in zero-shuffle sigma order (R6-proven pattern)
// Denominator: lanes l31>=16 use constant ones vf (lane 16 = exact ones column).
// No LDS, no barriers -> waves fully independent; unroll-4 hoists loads for latency hiding.
__global__ __launch_bounds__(256, 4) void attn_kernel(
    const ushort* __restrict__ Qh, const ushort* __restrict__ Kh,
    const ushort* __restrict__ Vtg, ushort* __restrict__ aout) {
  const int tid = threadIdx.x;
  const int lane = tid & 63, wv = tid >> 6;
  const int l31 = lane & 31, hi = lane >> 5;
  const int bh = blockIdx.x, qt = blockIdx.y;
  const int q0 = qt * 128 + wv * 32;
  const h8 qf = *reinterpret_cast<const h8*>(Qh + ((size_t)bh * NS + q0 + l31) * 16 + hi * 8);
  f32x16 oac0, oac1, zc;
#pragma unroll
  for (int i = 0; i < 16; ++i) { oac0[i] = 0.f; oac1[i] = 0.f; zc[i] = 0.f; }
  const int vrow = (l31 < 16) ? l31 : 0;  // clamped; lanes >=16 override with ones
  const bool vones = (l31 >= 16);
  const uint ONES2 = 0x3C003C00u;  // packed f16 {1.0, 1.0}
  const ushort* kp = Kh + (size_t)bh * NS * 16 + l31 * 16 + hi * 8;
  const ushort* Vr = Vtg + (size_t)bh * 16 * NS + (size_t)vrow * NS + hi * 4;

#pragma unroll 4
  for (int c = 0; c < 64; ++c) {
    const int kb = c * 32;
    const h8 kf = *reinterpret_cast<const h8*>(kp + (size_t)kb * 16);
    f32x16 sc = __builtin_amdgcn_mfma_f32_32x32x16_f16(kf, qf, zc, 0, 0, 0);
    float pr[16];
#pragma unroll
    for (int r = 0; r < 16; ++r) pr[r] = fast_exp2(sc[r]);
    {  // chunk 0: keys [kb, kb+16), sigma order: {hi*4..+3} and {8+hi*4..+3}
      union { uint u[4]; h8 h; } pf;
      pf.u[0] = pkrtz_u(pr[0], pr[1]);
      pf.u[1] = pkrtz_u(pr[2], pr[3]);
      pf.u[2] = pkrtz_u(pr[4], pr[5]);
      pf.u[3] = pkrtz_u(pr[6], pr[7]);
      const uint2 va = *reinterpret_cast<const uint2*>(Vr + kb);
      const uint2 vb = *reinterpret_cast<const uint2*>(Vr + kb + 8);
      union { uint u[4]; h8 h; } vv;
      vv.u[0] = vones ? ONES2 : va.x;
      vv.u[1] = vones ? ONES2 : va.y;
      vv.u[2] = vones ? ONES2 : vb.x;
      vv.u[3] = vones ? ONES2 : vb.y;
      oac0 = __builtin_amdgcn_mfma_f32_32x32x16_f16(pf.h, vv.h, oac0, 0, 0, 0);
    }
    {  // chunk 1: keys [kb+16, kb+32)
      union { uint u[4]; h8 h; } pf;
      pf.u[0] = pkrtz_u(pr[8], pr[9]);
      pf.u[1] = pkrtz_u(pr[10], pr[11]);
      pf.u[2] = pkrtz_u(pr[12], pr[13]);
      pf.u[3] = pkrtz_u(pr[14], pr[15]);
      const uint2 va = *reinterpret_cast<const uint2*>(Vr + kb + 16);
      const uint2 vb = *reinterpret_cast<const uint2*>(Vr + kb + 24);
      union { uint u[4]; h8 h; } vv;
      vv.u[0] = vones ? ONES2 : va.x;
      vv.u[1] = vones ? ONES2 : va.y;
      vv.u[2] = vones ? ONES2 : vb.x;
      vv.u[3] = vones ? ONES2 : vb.y;
      oac1 = __builtin_amdgcn_mfma_f32_32x32x16_f16(pf.h, vv.h, oac1, 0, 0, 0);
    }
  }
  const int b = bh >> 3, h = bh & 7;
  const int d = l31;
#pragma unroll
  for (int r = 0; r < 16; ++r) {
    float ov = oac0[r] + oac1[r];
    float ls = __shfl(ov, 16 + (hi << 5), 64);
    if (d < 16) {
      int qrow = q0 + ((r & 3) + ((r >> 2) << 3) + (hi << 2));
      aout[((size_t)(b * NS + qrow)) * 128 + h * 16 + d] = f2h(ov / ls);
    }
  }
}

// =================== kernel 3: output projection via f16 MFMA (R13 version) ===================
__global__ __launch_bounds__(256) void out_mfma(
    const ushort* __restrict__ Ain, const float* __restrict__ Wo,
    const float* __restrict__ bo, float* __restrict__ out) {
  __shared__ __align__(16) ushort Wt[128 * 136];
  __shared__ __align__(16) ushort Al[32 * 136];
  const int tid = threadIdx.x;
  const int rbase = blockIdx.x * 32;
  {
    const int n = tid & 127, kg = tid >> 7;
#pragma unroll
    for (int k8 = 0; k8 < 8; ++k8) {
      int k0 = k8 * 16 + kg * 8;
      float w[8];
#pragma unroll
      for (int j = 0; j < 8; ++j) w[j] = Wo[(k0 + j) * 128 + n];
      uint4 pk;
      pk.x = pkrtz_u(w[0], w[1]);
      pk.y = pkrtz_u(w[2], w[3]);
      pk.z = pkrtz_u(w[4], w[5]);
      pk.w = pkrtz_u(w[6], w[7]);
      *reinterpret_cast<uint4*>(&Wt[n * 136 + k0]) = pk;
    }
  }
#pragma unroll
  for (int it = 0; it < 2; ++it) {
    int fl = it * 256 + tid;
    int r = fl >> 4, c8 = (fl & 15) * 8;
    *reinterpret_cast<short8*>(&Al[r * 136 + c8]) =
        *reinterpret_cast<const short8*>(Ain + (size_t)(rbase + r) * 128 + c8);
  }
  __syncthreads();
  const int lane = tid & 63, wid = tid >> 6;
  const int l31 = lane & 31, hi = lane >> 5;
  f32x16 acc;
#pragma unroll
  for (int j = 0; j < 16; ++j) acc[j] = 0.f;
  const ushort* arow = &Al[l31 * 136 + hi * 8];
#pragma unroll
  for (int kk = 0; kk < 8; ++kk) {
    const h8 af = *reinterpret_cast<const h8*>(arow + kk * 16);
    const h8 bf = *reinterpret_cast<const h8*>(&Wt[(wid * 32 + l31) * 136 + kk * 16 + hi * 8]);
    acc = __builtin_amdgcn_mfma_f32_32x32x16_f16(af, bf, acc, 0, 0, 0);
  }
  const int c = wid * 32 + l31;
  const float bb = bo[c];
#pragma unroll
  for (int r = 0; r < 16; ++r) {
    int s = rbase + ((r & 3) + ((r >> 2) << 3) + (hi << 2));
    out[(size_t)s * 128 + c] = acc[r] + bb;
  }
}

extern "C" void kernel_launch(void* const* d_in, const int* in_sizes, int n_in,
                              void* d_out, int out_size, void* d_ws, size_t ws_size,
                              hipStream_t stream) {
  const float* q  = (const float*)d_in[0];
  const float* k  = (const float*)d_in[1];
  const float* v  = (const float*)d_in[2];
  const float* Wq = (const float*)d_in[3];
  const float* bq = (const float*)d_in[4];
  const float* Wk = (const float*)d_in[5];
  const float* bk = (const float*)d_in[6];
  const float* Wv = (const float*)d_in[7];
  const float* bv = (const float*)d_in[8];
  const float* Wo = (const float*)d_in[9];
  const float* bo = (const float*)d_in[10];
  float* out = (float*)d_out;

  // Qh|Kh (8MB f16) live in d_out (fully overwritten by out_mfma at the end).
  // d_ws: Vt (4MB) + aout f16 (4MB) = 8MB.
  ushort* Qh = (ushort*)d_out;
  ushort* Kh = Qh + 2097152;
  ushort* Vt = (ushort*)d_ws;
  ushort* aout = Vt + 2097152;

  hipLaunchKernelGGL(qkv_mfma, dim3(256, 3), dim3(256), 0, stream,
                     q, k, v, Wq, bq, Wk, bk, Wv, bv, Qh, Kh, Vt);
  hipLaunchKernelGGL(attn_kernel, dim3(64, 16), dim3(256), 0, stream, Qh, Kh, Vt, aout);
  hipLaunchKernelGGL(out_mfma, dim3(512), dim3(256), 0, stream, aout, Wo, bo, out);
}

// Round 15
// 56.724 us; speedup vs baseline: 1.8253x; 1.8253x over previous
//
#include <hip/hip_runtime.h>

typedef __attribute__((ext_vector_type(8))) short short8;
typedef __attribute__((ext_vector_type(16))) float f32x16;
typedef _Float16 h8 __attribute__((ext_vector_type(8)));
typedef unsigned int uint;
typedef unsigned short ushort;

#define NS 2048
#define QSCALE 0.0901684400555602f  // log2(e)/16, folded into Wq/bq

__device__ __forceinline__ ushort f2h(float f) {
  _Float16 h = (_Float16)f;
  return __builtin_bit_cast(ushort, h);
}
// two f32 -> packed 2xf16 (round toward zero)
__device__ __forceinline__ uint pkrtz_u(float a, float b) {
  uint r;
  asm("v_cvt_pkrtz_f16_f32 %0, %1, %2" : "=v"(r) : "v"(a), "v"(b));
  return r;
}
__device__ __forceinline__ float fast_exp2(float x) {
#if __has_builtin(__builtin_amdgcn_exp2f)
  return __builtin_amdgcn_exp2f(x);
#else
  return exp2f(x);
#endif
}

// =================== kernel 1: QKV projections via f16 MFMA (64-row tiles) ===================
// p=0: Q (scaled by QSCALE) -> Qh [BH][S][16] f16 ; p=1: K -> Kh ; p=2: V -> Vt [BH*16][S]
// 64-row tiles: grid 256x3 = 768 blocks = 3/CU -> latency hiding.
__global__ __launch_bounds__(256) void qkv_mfma(
    const float* __restrict__ qin, const float* __restrict__ kin, const float* __restrict__ vin,
    const float* __restrict__ Wq, const float* __restrict__ bq,
    const float* __restrict__ Wk, const float* __restrict__ bk,
    const float* __restrict__ Wv, const float* __restrict__ bv,
    ushort* __restrict__ Qh, ushort* __restrict__ Kh, ushort* __restrict__ Vt) {
  __shared__ __align__(16) ushort Wt[128 * 136];  // Wt[n][k], stride 136
  __shared__ __align__(16) ushort Al[64 * 136];   // Al[m][k]
  const int tid = threadIdx.x;
  const int p = blockIdx.y;
  const float* A = (p == 0) ? qin : (p == 1) ? kin : vin;
  const float* W = (p == 0) ? Wq : (p == 1) ? Wk : Wv;
  const float* bias = (p == 0) ? bq : (p == 1) ? bk : bv;
  const float wscale = (p == 0) ? QSCALE : 1.0f;
  const int rbase = blockIdx.x * 64;
  {
    const int n = tid & 127, kg = tid >> 7;
#pragma unroll
    for (int k8 = 0; k8 < 8; ++k8) {
      int k0 = k8 * 16 + kg * 8;
      float w[8];
#pragma unroll
      for (int j = 0; j < 8; ++j) w[j] = W[(k0 + j) * 128 + n] * wscale;
      uint4 pk;
      pk.x = pkrtz_u(w[0], w[1]);
      pk.y = pkrtz_u(w[2], w[3]);
      pk.z = pkrtz_u(w[4], w[5]);
      pk.w = pkrtz_u(w[6], w[7]);
      *reinterpret_cast<uint4*>(&Wt[n * 136 + k0]) = pk;
    }
  }
#pragma unroll
  for (int it = 0; it < 8; ++it) {
    int fl = it * 256 + tid;
    int r = fl >> 5, c4 = (fl & 31) << 2;
    float4 a = *reinterpret_cast<const float4*>(A + (size_t)(rbase + r) * 128 + c4);
    uint2 pk;
    pk.x = pkrtz_u(a.x, a.y);
    pk.y = pkrtz_u(a.z, a.w);
    *reinterpret_cast<uint2*>(&Al[r * 136 + c4]) = pk;
  }
  __syncthreads();
  const int lane = tid & 63, wid = tid >> 6;
  const int l31 = lane & 31, hi = lane >> 5;
  const int rh = wid >> 1, ch = wid & 1;  // wave -> (row-32-tile, col-64-tile)
  f32x16 acc[2];
#pragma unroll
  for (int i = 0; i < 2; ++i)
#pragma unroll
    for (int j = 0; j < 16; ++j) acc[i][j] = 0.f;
  const ushort* arow = &Al[(rh * 32 + l31) * 136 + hi * 8];
#pragma unroll
  for (int kk = 0; kk < 8; ++kk) {
    const h8 af = *reinterpret_cast<const h8*>(arow + kk * 16);
#pragma unroll
    for (int i = 0; i < 2; ++i) {
      int nt = ch * 2 + i;
      const h8 bf = *reinterpret_cast<const h8*>(&Wt[(nt * 32 + l31) * 136 + kk * 16 + hi * 8]);
      acc[i] = __builtin_amdgcn_mfma_f32_32x32x16_f16(af, bf, acc[i], 0, 0, 0);
    }
  }
  const int bI = rbase >> 11;
  if (p < 2) {
    ushort* outp = (p == 0) ? Qh : Kh;
#pragma unroll
    for (int i = 0; i < 2; ++i) {
      int c = (ch * 2 + i) * 32 + l31;
      int h = c >> 4, d = c & 15;
      float bb = bias[c] * wscale;
#pragma unroll
      for (int r = 0; r < 16; ++r) {
        int s = rbase + rh * 32 + ((r & 3) + ((r >> 2) << 3) + (hi << 2));
        int sl = s & 2047;
        outp[((size_t)((bI << 3) + h) * 2048 + sl) * 16 + d] = f2h(acc[i][r] + bb);
      }
    }
  } else {
    __syncthreads();
    ushort* CL = Wt;  // reuse as [c][s_local], stride 72 (144B, 16B-aligned)
#pragma unroll
    for (int i = 0; i < 2; ++i) {
      int c = (ch * 2 + i) * 32 + l31;
      float bb = bias[c];
#pragma unroll
      for (int g = 0; g < 4; ++g) {
        uint2 pk;
        pk.x = pkrtz_u(acc[i][g * 4 + 0] + bb, acc[i][g * 4 + 1] + bb);
        pk.y = pkrtz_u(acc[i][g * 4 + 2] + bb, acc[i][g * 4 + 3] + bb);
        int sl0 = rh * 32 + g * 8 + (hi << 2);
        *reinterpret_cast<uint2*>(&CL[c * 72 + sl0]) = pk;
      }
    }
    __syncthreads();
    const int slb = rbase & 2047;
#pragma unroll
    for (int it = 0; it < 4; ++it) {
      int fl = it * 256 + tid;           // 0..1023
      int c = fl >> 3, s8 = (fl & 7) * 8;  // 128 cols x 8 chunks
      short8 val = *reinterpret_cast<const short8*>(&CL[c * 72 + s8]);
      int h = c >> 4, d = c & 15;
      *reinterpret_cast<short8*>(&Vt[((size_t)((bI << 3) + h) * 16 + d) * 2048 + slb + s8]) = val;
    }
  }
}

// =================== kernel 2: flash attention (R11/R13 version) ===================
// Grid (bh=x, qt=y): all 16 q-tiles of a head share one XCD (K/V L2-resident).
// swapped QK^T: sc = mfma(K, Q^T) = score*log2(e)/16; P = exp2(sc).
// V stored in LDS sigma-permuted (slot = key with bits 2<->3 swapped within each
// 16-group), matching the A-fragment's k-slot->key map -> PV B-frag is ONE ds_read_b128.
// Denominator via ones-row 16 of Vl (acc col 16 = sum P).
__global__ __launch_bounds__(256, 4) void attn_kernel(
    const ushort* __restrict__ Qh, const ushort* __restrict__ Kh,
    const ushort* __restrict__ Vtg, ushort* __restrict__ aout) {
  __shared__ __align__(16) ushort Kl[256 * 24];   // [key][16d], 48B stride
  __shared__ __align__(16) ushort Vl[17 * 264];   // [17d][256 sigma-slots], row16 = ones
  const int tid = threadIdx.x;
  const int lane = tid & 63, wv = tid >> 6;
  const int l31 = lane & 31, hi = lane >> 5;
  const int bh = blockIdx.x, qt = blockIdx.y;
  for (int e = tid; e < 264; e += 256) Vl[16 * 264 + e] = 0x3C00;  // f16 1.0
  const int q0 = qt * 128 + wv * 32;
  const h8 qf = *reinterpret_cast<const h8*>(Qh + ((size_t)bh * NS + q0 + l31) * 16 + hi * 8);
  f32x16 oac0, oac1, zc;
#pragma unroll
  for (int i = 0; i < 16; ++i) { oac0[i] = 0.f; oac1[i] = 0.f; zc[i] = 0.f; }
  const int vrow = (l31 < 17) ? l31 : 16;
  const ushort* Kg = Kh + (size_t)bh * NS * 16;
  const ushort* Vg = Vtg + (size_t)bh * 16 * NS;
  const ushort* kbl = &Kl[l31 * 24 + hi * 8];
  const ushort* vbase = &Vl[vrow * 264 + hi * 8];
  const int key0 = tid >> 1, hh = tid & 1, vd = tid >> 5, vc = (tid & 31) * 8;
  // sigma staging: this thread's 8 keys [vc, vc+8): first 4 -> slots vs1..+3,
  // second 4 -> slots vs1+8..+11  (vs1 = slot of key vc; bits 2<->3 swap)
  const int vgrp = vc & ~31, vk0 = vc & 31;
  const int vs1 = vgrp + ((vk0 & 16) | ((vk0 & 8) >> 1));

  short8 rk0, rk1, rv0, rv1;
#define LOADT(T)                                                                          \
  {                                                                                       \
    int kb = (T) * 256;                                                                   \
    rk0 = *reinterpret_cast<const short8*>(Kg + (size_t)(kb + key0) * 16 + hh * 8);       \
    rk1 = *reinterpret_cast<const short8*>(Kg + (size_t)(kb + 128 + key0) * 16 + hh * 8); \
    rv0 = *reinterpret_cast<const short8*>(Vg + (size_t)vd * NS + kb + vc);               \
    rv1 = *reinterpret_cast<const short8*>(Vg + (size_t)(8 + vd) * NS + kb + vc);         \
  }
#define WRITET()                                                                          \
  {                                                                                       \
    *reinterpret_cast<short8*>(&Kl[key0 * 24 + hh * 8]) = rk0;                            \
    *reinterpret_cast<short8*>(&Kl[(128 + key0) * 24 + hh * 8]) = rk1;                    \
    union { short8 s; uint2 u[2]; } c0, c1;                                               \
    c0.s = rv0; c1.s = rv1;                                                               \
    *reinterpret_cast<uint2*>(&Vl[vd * 264 + vs1]) = c0.u[0];                             \
    *reinterpret_cast<uint2*>(&Vl[vd * 264 + vs1 + 8]) = c0.u[1];                         \
    *reinterpret_cast<uint2*>(&Vl[(8 + vd) * 264 + vs1]) = c1.u[0];                       \
    *reinterpret_cast<uint2*>(&Vl[(8 + vd) * 264 + vs1 + 8]) = c1.u[1];                   \
  }

  LOADT(0);
  WRITET();
  __syncthreads();
  for (int t = 0; t < 8; ++t) {
    if (t < 7) LOADT(t + 1);  // in flight during compute; single LDS buffer
#pragma unroll
    for (int kt = 0; kt < 8; ++kt) {
      const h8 kf = *reinterpret_cast<const h8*>(kbl + kt * 768);
      f32x16 sc = __builtin_amdgcn_mfma_f32_32x32x16_f16(kf, qf, zc, 0, 0, 0);
      float pr[16];
#pragma unroll
      for (int r = 0; r < 16; ++r) pr[r] = fast_exp2(sc[r]);
      {  // chunk 0: keys [kt*32, +16), sigma-ordered on both sides
        union { uint u[4]; h8 h; } pf;
        pf.u[0] = pkrtz_u(pr[0], pr[1]);
        pf.u[1] = pkrtz_u(pr[2], pr[3]);
        pf.u[2] = pkrtz_u(pr[4], pr[5]);
        pf.u[3] = pkrtz_u(pr[6], pr[7]);
        const h8 vf = *reinterpret_cast<const h8*>(vbase + kt * 32);
        oac0 = __builtin_amdgcn_mfma_f32_32x32x16_f16(pf.h, vf, oac0, 0, 0, 0);
      }
      {  // chunk 1: keys [kt*32+16, +16)
        union { uint u[4]; h8 h; } pf;
        pf.u[0] = pkrtz_u(pr[8], pr[9]);
        pf.u[1] = pkrtz_u(pr[10], pr[11]);
        pf.u[2] = pkrtz_u(pr[12], pr[13]);
        pf.u[3] = pkrtz_u(pr[14], pr[15]);
        const h8 vf = *reinterpret_cast<const h8*>(vbase + kt * 32 + 16);
        oac1 = __builtin_amdgcn_mfma_f32_32x32x16_f16(pf.h, vf, oac1, 0, 0, 0);
      }
    }
    if (t < 7) {
      __syncthreads();  // all waves done reading buffer
      WRITET();
      __syncthreads();  // buffer ready
    }
  }
#undef LOADT
#undef WRITET
  const int b = bh >> 3, h = bh & 7;
  const int d = l31;
#pragma unroll
  for (int r = 0; r < 16; ++r) {
    float ov = oac0[r] + oac1[r];
    float ls = __shfl(ov, 16 + (hi << 5), 64);
    if (d < 16) {
      int qrow = q0 + ((r & 3) + ((r >> 2) << 3) + (hi << 2));
      aout[((size_t)(b * NS + qrow)) * 128 + h * 16 + d] = f2h(ov / ls);
    }
  }
}

// =================== kernel 3: output projection via f16 MFMA (32-row tiles) ===================
__global__ __launch_bounds__(256) void out_mfma(
    const ushort* __restrict__ Ain, const float* __restrict__ Wo,
    const float* __restrict__ bo, float* __restrict__ out) {
  __shared__ __align__(16) ushort Wt[128 * 136];
  __shared__ __align__(16) ushort Al[32 * 136];
  const int tid = threadIdx.x;
  const int rbase = blockIdx.x * 32;
  {
    const int n = tid & 127, kg = tid >> 7;
#pragma unroll
    for (int k8 = 0; k8 < 8; ++k8) {
      int k0 = k8 * 16 + kg * 8;
      float w[8];
#pragma unroll
      for (int j = 0; j < 8; ++j) w[j] = Wo[(k0 + j) * 128 + n];
      uint4 pk;
      pk.x = pkrtz_u(w[0], w[1]);
      pk.y = pkrtz_u(w[2], w[3]);
      pk.z = pkrtz_u(w[4], w[5]);
      pk.w = pkrtz_u(w[6], w[7]);
      *reinterpret_cast<uint4*>(&Wt[n * 136 + k0]) = pk;
    }
  }
#pragma unroll
  for (int it = 0; it < 2; ++it) {
    int fl = it * 256 + tid;
    int r = fl >> 4, c8 = (fl & 15) * 8;
    *reinterpret_cast<short8*>(&Al[r * 136 + c8]) =
        *reinterpret_cast<const short8*>(Ain + (size_t)(rbase + r) * 128 + c8);
  }
  __syncthreads();
  const int lane = tid & 63, wid = tid >> 6;
  const int l31 = lane & 31, hi = lane >> 5;
  f32x16 acc;
#pragma unroll
  for (int j = 0; j < 16; ++j) acc[j] = 0.f;
  const ushort* arow = &Al[l31 * 136 + hi * 8];
#pragma unroll
  for (int kk = 0; kk < 8; ++kk) {
    const h8 af = *reinterpret_cast<const h8*>(arow + kk * 16);
    const h8 bf = *reinterpret_cast<const h8*>(&Wt[(wid * 32 + l31) * 136 + kk * 16 + hi * 8]);
    acc = __builtin_amdgcn_mfma_f32_32x32x16_f16(af, bf, acc, 0, 0, 0);
  }
  const int c = wid * 32 + l31;
  const float bb = bo[c];
#pragma unroll
  for (int r = 0; r < 16; ++r) {
    int s = rbase + ((r & 3) + ((r >> 2) << 3) + (hi << 2));
    out[(size_t)s * 128 + c] = acc[r] + bb;
  }
}

extern "C" void kernel_launch(void* const* d_in, const int* in_sizes, int n_in,
                              void* d_out, int out_size, void* d_ws, size_t ws_size,
                              hipStream_t stream) {
  const float* q  = (const float*)d_in[0];
  const float* k  = (const float*)d_in[1];
  const float* v  = (const float*)d_in[2];
  const float* Wq = (const float*)d_in[3];
  const float* bq = (const float*)d_in[4];
  const float* Wk = (const float*)d_in[5];
  const float* bk = (const float*)d_in[6];
  const float* Wv = (const float*)d_in[7];
  const float* bv = (const float*)d_in[8];
  const float* Wo = (const float*)d_in[9];
  const float* bo = (const float*)d_in[10];
  float* out = (float*)d_out;

  // Qh|Kh (8MB f16) live in d_out (fully overwritten by out_mfma at the end).
  // d_ws: Vt (4MB) + aout f16 (4MB) = 8MB.
  ushort* Qh = (ushort*)d_out;
  ushort* Kh = Qh + 2097152;
  ushort* Vt = (ushort*)d_ws;
  ushort* aout = Vt + 2097152;

  hipLaunchKernelGGL(qkv_mfma, dim3(256, 3), dim3(256), 0, stream,
                     q, k, v, Wq, bq, Wk, bk, Wv, bv, Qh, Kh, Vt);
  hipLaunchKernelGGL(attn_kernel, dim3(64, 16), dim3(256), 0, stream, Qh, Kh, Vt, aout);
  hipLaunchKernelGGL(out_mfma, dim3(512), dim3(256), 0, stream, aout, Wo, bo, out);
}